// Round 4
// baseline (817.411 us; speedup 1.0000x reference)
//
#include <hip/hip_runtime.h>
#include <stdint.h>
#include <stddef.h>

#define NNODES 100000
#define NEDGES 3200000
#define INFEAT 512
#define HID 256
#define SMP 32768
#define BNEPS 1e-5f
#define NCOPY 32

__device__ __forceinline__ uint32_t rotl32(uint32_t x, int d) { return (x << d) | (x >> (32 - d)); }

// Threefry-2x32, 20 rounds, JAX key-injection schedule — bit-exact, DO NOT TOUCH (verified R1)
__device__ __forceinline__ void threefry2x32(uint32_t k0, uint32_t k1, uint32_t& x0, uint32_t& x1) {
  const uint32_t ks0 = k0, ks1 = k1, ks2 = k0 ^ k1 ^ 0x1BD11BDAu;
  x0 += ks0; x1 += ks1;
#define TFR(r) { x0 += x1; x1 = rotl32(x1, r); x1 ^= x0; }
  TFR(13) TFR(15) TFR(26) TFR(6)
  x0 += ks1; x1 += ks2 + 1u;
  TFR(17) TFR(29) TFR(16) TFR(24)
  x0 += ks2; x1 += ks0 + 2u;
  TFR(13) TFR(15) TFR(26) TFR(6)
  x0 += ks0; x1 += ks1 + 3u;
  TFR(17) TFR(29) TFR(16) TFR(24)
  x0 += ks1; x1 += ks2 + 4u;
  TFR(13) TFR(15) TFR(26) TFR(6)
  x0 += ks2; x1 += ks0 + 5u;
#undef TFR
}

// 32-copy histogram: copy = blockIdx & 31 (aligned with XCD round-robin since 32 % 8 == 0)
__global__ __launch_bounds__(256) void k_deg_part(const int* __restrict__ erow, int* __restrict__ degc) {
  int* mydeg = degc + (size_t)(blockIdx.x & (NCOPY - 1)) * NNODES;
  const int t = blockIdx.x * 256 + threadIdx.x;       // 400128 threads, 8 edges each
  const int base = t * 8;
  if (base >= NEDGES) return;
  int4 a = *(const int4*)(erow + base);
  int4 b = *(const int4*)(erow + base + 4);
  atomicAdd(&mydeg[a.x], 1); atomicAdd(&mydeg[a.y], 1);
  atomicAdd(&mydeg[a.z], 1); atomicAdd(&mydeg[a.w], 1);
  atomicAdd(&mydeg[b.x], 1); atomicAdd(&mydeg[b.y], 1);
  atomicAdd(&mydeg[b.z], 1); atomicAdd(&mydeg[b.w], 1);
}

__global__ __launch_bounds__(256) void k_deg_reduce(const int* __restrict__ degc, int* __restrict__ deg) {
  int i = blockIdx.x * 256 + threadIdx.x;
  if (i >= NNODES) return;
  int s = 0;
#pragma unroll
  for (int c = 0; c < NCOPY; ++c) s += degc[(size_t)c * NNODES + i];
  deg[i] = s;
}

// ---- cumsum = bit-exact replica of XLA associative_scan tree, parallelized ----
__global__ __launch_bounds__(256) void k_down(const int* __restrict__ deg, float* __restrict__ E) {
  __shared__ float l0[4096];
  __shared__ float l1[2048];
  const int t = threadIdx.x;
  const int base0 = blockIdx.x * 4096;
  const int n0 = min(4096, NNODES - base0);
  for (int i = t; i < n0; i += 256) {
    float p = (float)deg[base0 + i] / 3200000.0f;  // deg.sum() exactly 3.2e6 in f32
    l0[i] = p;
    E[base0 + i] = p;
  }
  __syncthreads();
  const int b1 = base0 >> 1, n1 = min(2048, 50000 - b1);
  for (int k = t; k < n1; k += 256) { float v = l0[2*k] + l0[2*k+1]; l1[k] = v; E[100000 + b1 + k] = v; }
  __syncthreads();
  const int b2 = base0 >> 2, n2 = min(1024, 25000 - b2);
  for (int k = t; k < n2; k += 256) { float v = l1[2*k] + l1[2*k+1]; l0[k] = v; E[150000 + b2 + k] = v; }
  __syncthreads();
  const int b3 = base0 >> 3, n3 = min(512, 12500 - b3);
  for (int k = t; k < n3; k += 256) { float v = l0[2*k] + l0[2*k+1]; l1[k] = v; E[175000 + b3 + k] = v; }
  __syncthreads();
  const int b4 = base0 >> 4, n4 = min(256, 6250 - b4);
  for (int k = t; k < n4; k += 256) { float v = l1[2*k] + l1[2*k+1]; E[187500 + b4 + k] = v; }
}

__device__ __constant__ int kMidN[12] = {3125,1562,781,390,195,97,48,24,12,6,3,1};
__device__ __constant__ int kMidO[12] = {0,3125,4687,5468,5858,6053,6150,6198,6222,6234,6240,6243};
__global__ __launch_bounds__(1024) void k_mid(const float* __restrict__ E, float* __restrict__ CS) {
  __shared__ float eb[6244];
  __shared__ float sb[6244];
  const int t = threadIdx.x;
  const float* e4 = E + 187500;
  for (int k = t; k < 3125; k += 1024) eb[k] = e4[2*k] + e4[2*k+1];
  __syncthreads();
  for (int li = 1; li < 12; ++li) {
    const float* src = eb + kMidO[li-1];
    float* dst = eb + kMidO[li];
    const int n = kMidN[li];
    for (int k = t; k < n; k += 1024) dst[k] = src[2*k] + src[2*k+1];
    __syncthreads();
  }
  if (t == 0) sb[6243] = eb[6243];  // s16 = e16
  __syncthreads();
  for (int li = 10; li >= 0; --li) {
    const float* el = eb + kMidO[li];
    const float* sh = sb + kMidO[li+1];
    float* sl = sb + kMidO[li];
    const int n = kMidN[li], nh = kMidN[li+1];
    for (int k = t; k < nh; k += 1024) {
      float v = sh[k];
      sl[2*k+1] = v;
      if (2*k+2 < n) sl[2*k+2] = v + el[2*k+2];
    }
    if (t == 0) sl[0] = el[0];
    __syncthreads();
  }
  for (int k = t; k < 3125; k += 1024) CS[193750 + k] = sb[k];  // s5
}

__global__ __launch_bounds__(256) void k_up(const float* __restrict__ sh, const float* __restrict__ el,
                                            float* __restrict__ sl, int n) {
  int j = blockIdx.x * 256 + threadIdx.x;
  if (j >= n) return;
  if (j == 0) { sl[0] = el[0]; return; }
  float v = sh[(j - 1) >> 1];
  sl[j] = (j & 1) ? v : v + el[j];
}

// partitionable-threefry choice + searchsorted left — bit-exact, verified R1
__global__ __launch_bounds__(256) void k_sample(const float* __restrict__ cum, int* __restrict__ sampled,
                                                int* __restrict__ mapping, float* __restrict__ outSamp) {
  int i = blockIdx.x * 256 + threadIdx.x;
  if (i >= SMP) return;
  uint32_t x0 = 0u, x1 = (uint32_t)i;
  threefry2x32(0u, 42u, x0, x1);
  uint32_t bits = x0 ^ x1;
  float u = __uint_as_float((bits >> 9) | 0x3f800000u) - 1.0f;
  float r = cum[NNODES - 1] * (1.0f - u);
  int lo = 0, hi = NNODES;
  while (lo < hi) {
    int mid = (lo + hi) >> 1;
    if (cum[mid] < r) lo = mid + 1; else hi = mid;
  }
  if (lo > NNODES - 1) lo = NNODES - 1;
  sampled[i] = lo;
  outSamp[i] = (float)lo;
  atomicMax(&mapping[lo], i);
}

// ---- CSR build over valid edges keyed by destination position ----
__global__ __launch_bounds__(256) void k_edge_count(const int* __restrict__ erow, const int* __restrict__ ecol,
                                                    const int* __restrict__ mapping, int* __restrict__ cnt) {
  int i = blockIdx.x * 256 + threadIdx.x;
  if (i >= NEDGES) return;
  int r = mapping[erow[i]];
  int c = mapping[ecol[i]];
  if ((r | c) >= 0) atomicAdd(&cnt[c], 1);
}

__global__ __launch_bounds__(1024) void k_scan(const int* __restrict__ cnt, int* __restrict__ rowptr,
                                               int* __restrict__ cursor) {
  __shared__ int tot[1024];
  const int t = threadIdx.x;
  const int base = t * 32;
  int local[32];
  int s = 0;
#pragma unroll
  for (int i = 0; i < 32; ++i) { local[i] = s; s += cnt[base + i]; }
  tot[t] = s;
  __syncthreads();
  for (int o = 1; o < 1024; o <<= 1) {
    int v = (t >= o) ? tot[t - o] : 0;
    __syncthreads();
    tot[t] += v;
    __syncthreads();
  }
  int excl = (t == 0) ? 0 : tot[t - 1];
#pragma unroll
  for (int i = 0; i < 32; ++i) {
    int v = excl + local[i];
    rowptr[base + i] = v;
    cursor[base + i] = v;
  }
  if (t == 1023) rowptr[SMP] = tot[1023];
}

__global__ __launch_bounds__(256) void k_edge_fill(const int* __restrict__ erow, const int* __restrict__ ecol,
                                                   const int* __restrict__ mapping, int* __restrict__ cursor,
                                                   int* __restrict__ srcidx) {
  int i = blockIdx.x * 256 + threadIdx.x;
  if (i >= NEDGES) return;
  int r = mapping[erow[i]];
  int c = mapping[ecol[i]];
  if ((r | c) < 0) return;
  int pos = atomicAdd(&cursor[c], 1);
  srcidx[pos] = r;
}

// A[c,:] = sum over CSR bucket of S[r,:] — one wave per destination, no atomics
__global__ __launch_bounds__(256) void k_segsum(const float* __restrict__ S, const int* __restrict__ rowptr,
                                                const int* __restrict__ srcidx, float* __restrict__ A) {
  const int wave = threadIdx.x >> 6, lane = threadIdx.x & 63;
  const int c = blockIdx.x * 4 + wave;
  const int b = rowptr[c], e = rowptr[c + 1];
  float4 acc = make_float4(0.f, 0.f, 0.f, 0.f);
  for (int i = b; i < e; ++i) {
    int r = srcidx[i];
    float4 v = *(const float4*)(S + (size_t)r * HID + lane * 4);
    acc.x += v.x; acc.y += v.y; acc.z += v.z; acc.w += v.w;
  }
  *(float4*)(A + (size_t)c * HID + lane * 4) = acc;
}

// out[c] = sum s3[r] + b3 — one thread per destination
__global__ __launch_bounds__(256) void k_segsum_sc(const float* __restrict__ s3, const int* __restrict__ rowptr,
                                                   const int* __restrict__ srcidx, const float* __restrict__ b3,
                                                   float* __restrict__ out) {
  int c = blockIdx.x * 256 + threadIdx.x;
  if (c >= SMP) return;
  float acc = 0.f;
  const int e = rowptr[c + 1];
  for (int i = rowptr[c]; i < e; ++i) acc += s3[srcidx[i]];
  out[c] = acc + b3[0];
}

// C[M=32768, N=256] = gather(A)[.,K] @ B[K,256]; 64x64 tile, 4x4/thread, fp32
__global__ __launch_bounds__(256) void k_gemm(const float* __restrict__ Am, const float* __restrict__ Bm,
                                              float* __restrict__ Cm, const int* __restrict__ gather, int K) {
  __shared__ float As[16][68];
  __shared__ float Bs[16][64];
  const int t = threadIdx.x;
  const int tx = t & 15, ty = t >> 4;
  const int row0 = blockIdx.x * 64, col0 = blockIdx.y * 64;
  const int ar = t >> 2, ak = (t & 3) << 2;
  int arow = row0 + ar;
  if (gather) arow = gather[arow];
  const float* aptr = Am + (size_t)arow * K + ak;
  const int kb = t >> 4, cb = (t & 15) << 2;
  const float* bptr = Bm + (size_t)kb * HID + col0 + cb;
  float acc[4][4] = {};
  for (int k0 = 0; k0 < K; k0 += 16) {
    float4 av = *(const float4*)(aptr + k0);
    float4 bv = *(const float4*)(bptr + (size_t)k0 * HID);
    As[ak + 0][ar] = av.x;
    As[ak + 1][ar] = av.y;
    As[ak + 2][ar] = av.z;
    As[ak + 3][ar] = av.w;
    *(float4*)&Bs[kb][cb] = bv;
    __syncthreads();
#pragma unroll
    for (int kk = 0; kk < 16; ++kk) {
      float4 a = *(const float4*)&As[kk][ty << 2];
      float4 b = *(const float4*)&Bs[kk][tx << 2];
      acc[0][0] = fmaf(a.x, b.x, acc[0][0]); acc[0][1] = fmaf(a.x, b.y, acc[0][1]);
      acc[0][2] = fmaf(a.x, b.z, acc[0][2]); acc[0][3] = fmaf(a.x, b.w, acc[0][3]);
      acc[1][0] = fmaf(a.y, b.x, acc[1][0]); acc[1][1] = fmaf(a.y, b.y, acc[1][1]);
      acc[1][2] = fmaf(a.y, b.z, acc[1][2]); acc[1][3] = fmaf(a.y, b.w, acc[1][3]);
      acc[2][0] = fmaf(a.z, b.x, acc[2][0]); acc[2][1] = fmaf(a.z, b.y, acc[2][1]);
      acc[2][2] = fmaf(a.z, b.z, acc[2][2]); acc[2][3] = fmaf(a.z, b.w, acc[2][3]);
      acc[3][0] = fmaf(a.w, b.x, acc[3][0]); acc[3][1] = fmaf(a.w, b.y, acc[3][1]);
      acc[3][2] = fmaf(a.w, b.z, acc[3][2]); acc[3][3] = fmaf(a.w, b.w, acc[3][3]);
    }
    __syncthreads();
  }
#pragma unroll
  for (int i = 0; i < 4; ++i) {
    float4 v = make_float4(acc[i][0], acc[i][1], acc[i][2], acc[i][3]);
    *(float4*)(Cm + (size_t)(row0 + (ty << 2) + i) * HID + col0 + (tx << 2)) = v;
  }
}

__global__ __launch_bounds__(256) void k_bn_stats(const float* __restrict__ A, const float* __restrict__ bias,
                                                  float* __restrict__ sums, float* __restrict__ sumsq) {
  const int c = threadIdx.x;
  const float b = bias[c];
  float s = 0.f, q = 0.f;
  const int r0 = blockIdx.x * (SMP / 256);
  for (int r = r0; r < r0 + (SMP / 256); ++r) {
    float h = A[(size_t)r * HID + c] + b;
    s += h;
    q = fmaf(h, h, q);
  }
  unsafeAtomicAdd(&sums[c], s);
  unsafeAtomicAdd(&sumsq[c], q);
}

__global__ __launch_bounds__(256) void k_bn_final(const float* __restrict__ sums, const float* __restrict__ sumsq,
    const float* __restrict__ gamma, const float* __restrict__ beta,
    float* __restrict__ scale, float* __restrict__ shift) {
  int c = threadIdx.x;
  float mu = sums[c] * (1.0f / SMP);
  float var = fmaxf(sumsq[c] * (1.0f / SMP) - mu * mu, 0.0f);
  float sc = gamma[c] / sqrtf(var + BNEPS);
  scale[c] = sc;
  shift[c] = beta[c] - mu * sc;
}

__global__ __launch_bounds__(256) void k_bn_apply(const float* __restrict__ A, const float* __restrict__ bias,
    const float* __restrict__ scale, const float* __restrict__ shift, float* __restrict__ Hh) {
  const int total = SMP * HID / 4;
  for (int i = blockIdx.x * 256 + threadIdx.x; i < total; i += gridDim.x * 256) {
    int c = (i & (HID / 4 - 1)) * 4;
    float4 v = ((const float4*)A)[i];
    v.x = fmaxf(fmaf(v.x + bias[c + 0], scale[c + 0], shift[c + 0]), 0.f);
    v.y = fmaxf(fmaf(v.y + bias[c + 1], scale[c + 1], shift[c + 1]), 0.f);
    v.z = fmaxf(fmaf(v.z + bias[c + 2], scale[c + 2], shift[c + 2]), 0.f);
    v.w = fmaxf(fmaf(v.w + bias[c + 3], scale[c + 3], shift[c + 3]), 0.f);
    ((float4*)Hh)[i] = v;
  }
}

// s3[i] = dot(H[i,:], W3[:,0]); one wave per row
__global__ __launch_bounds__(256) void k_gemv3(const float* __restrict__ Hh, const float* __restrict__ W3,
                                               float* __restrict__ s3) {
  const int wave = threadIdx.x >> 6, lane = threadIdx.x & 63;
  const int row = blockIdx.x * 4 + wave;
  float4 h = *(const float4*)(Hh + (size_t)row * HID + lane * 4);
  float4 w = *(const float4*)(W3 + lane * 4);
  float d = h.x * w.x + h.y * w.y + h.z * w.z + h.w * w.w;
#pragma unroll
  for (int o = 32; o > 0; o >>= 1) d += __shfl_down(d, o);
  if (lane == 0) s3[row] = d;
}

extern "C" void kernel_launch(void* const* d_in, const int* in_sizes, int n_in,
                              void* d_out, int out_size, void* d_ws, size_t ws_size,
                              hipStream_t stream) {
  (void)in_sizes; (void)n_in; (void)out_size; (void)ws_size;
  const float* x   = (const float*)d_in[0];
  const int*  eidx = (const int*)d_in[1];
  const float* W1  = (const float*)d_in[2];
  const float* b1  = (const float*)d_in[3];
  const float* W2  = (const float*)d_in[4];
  const float* b2  = (const float*)d_in[5];
  const float* W3  = (const float*)d_in[6];
  const float* b3  = (const float*)d_in[7];
  const float* g1  = (const float*)d_in[8];
  const float* be1 = (const float*)d_in[9];
  const float* g2  = (const float*)d_in[10];
  const float* be2 = (const float*)d_in[11];
  const int* erow = eidx;
  const int* ecol = eidx + NEDGES;

  float* out = (float*)d_out;        // [32768] conv3 output
  float* outSamp = out + SMP;        // [32768] sampled indices as f32

  size_t off = 0;
  auto take = [&](size_t bytes) -> char* {
    char* p = (char*)d_ws + off;
    off += (bytes + 255) & ~(size_t)255;
    return p;
  };
  float* S       = (float*)take((size_t)SMP * HID * 4);  // support / s3
  float* A       = (float*)take((size_t)SMP * HID * 4);  // segsum output
  float* H       = (float*)take((size_t)SMP * HID * 4);  // post-BN activations
  float* E       = (float*)take(199994 * 4);             // down-sweep levels
  float* CS      = (float*)take(199994 * 4);             // up-sweep levels (CS[0..100000) = result)
  int*   deg     = (int*)take(NNODES * 4);
  int*   degc    = (int*)take((size_t)NCOPY * NNODES * 4);  // 12.8 MB histogram copies
  int*   mapping = (int*)take(NNODES * 4);
  int*   sampled = (int*)take(SMP * 4);
  float* sums    = (float*)take(HID * 4 * 2);
  float* sumsq   = sums + HID;
  float* scale   = (float*)take(HID * 4);
  float* shift   = (float*)take(HID * 4);
  int*   cnt     = (int*)take(SMP * 4);
  int*   rowptr  = (int*)take((SMP + 1) * 4);
  int*   cursor  = (int*)take(SMP * 4);
  int*   srcidx  = (int*)take((size_t)NEDGES * 4);
  // total ws need ~= 128 MB

  hipMemsetAsync(degc, 0, (size_t)NCOPY * NNODES * 4, stream);
  hipMemsetAsync(mapping, 0xFF, NNODES * 4, stream);  // -1 everywhere
  hipMemsetAsync(cnt, 0, SMP * 4, stream);

  k_deg_part<<<(NEDGES / 8 + 255) / 256, 256, 0, stream>>>(erow, degc);
  k_deg_reduce<<<(NNODES + 255) / 256, 256, 0, stream>>>(degc, deg);

  // cumsum: parallel bit-exact tree
  k_down<<<25, 256, 0, stream>>>(deg, E);
  k_mid<<<1, 1024, 0, stream>>>(E, CS);
  k_up<<<(6250 + 255) / 256, 256, 0, stream>>>(CS + 193750, E + 187500, CS + 187500, 6250);
  k_up<<<(12500 + 255) / 256, 256, 0, stream>>>(CS + 187500, E + 175000, CS + 175000, 12500);
  k_up<<<(25000 + 255) / 256, 256, 0, stream>>>(CS + 175000, E + 150000, CS + 150000, 25000);
  k_up<<<(50000 + 255) / 256, 256, 0, stream>>>(CS + 150000, E + 100000, CS + 100000, 50000);
  k_up<<<(100000 + 255) / 256, 256, 0, stream>>>(CS + 100000, E, CS, 100000);

  k_sample<<<SMP / 256, 256, 0, stream>>>(CS, sampled, mapping, outSamp);

  // CSR over valid edges, keyed by destination position
  k_edge_count<<<(NEDGES + 255) / 256, 256, 0, stream>>>(erow, ecol, mapping, cnt);
  k_scan<<<1, 1024, 0, stream>>>(cnt, rowptr, cursor);
  k_edge_fill<<<(NEDGES + 255) / 256, 256, 0, stream>>>(erow, ecol, mapping, cursor, srcidx);

  // layer 1: conv(x@W1) -> BN -> relu
  k_gemm<<<dim3(SMP / 64, HID / 64), 256, 0, stream>>>(x, W1, S, sampled, INFEAT);
  k_segsum<<<SMP / 4, 256, 0, stream>>>(S, rowptr, srcidx, A);
  hipMemsetAsync(sums, 0, HID * 4 * 2, stream);
  k_bn_stats<<<256, 256, 0, stream>>>(A, b1, sums, sumsq);
  k_bn_final<<<1, HID, 0, stream>>>(sums, sumsq, g1, be1, scale, shift);
  k_bn_apply<<<2048, 256, 0, stream>>>(A, b1, scale, shift, H);

  // layer 2
  k_gemm<<<dim3(SMP / 64, HID / 64), 256, 0, stream>>>(H, W2, S, nullptr, HID);
  k_segsum<<<SMP / 4, 256, 0, stream>>>(S, rowptr, srcidx, A);
  hipMemsetAsync(sums, 0, HID * 4 * 2, stream);
  k_bn_stats<<<256, 256, 0, stream>>>(A, b2, sums, sumsq);
  k_bn_final<<<1, HID, 0, stream>>>(sums, sumsq, g2, be2, scale, shift);
  k_bn_apply<<<2048, 256, 0, stream>>>(A, b2, scale, shift, H);

  // layer 3: gemv + CSR segsum + bias
  k_gemv3<<<SMP / 4, 256, 0, stream>>>(H, W3, S);  // S reused as s3
  k_segsum_sc<<<SMP / 256, 256, 0, stream>>>(S, rowptr, srcidx, b3, out);
}

// Round 5
// 811.169 us; speedup vs baseline: 1.0077x; 1.0077x over previous
//
#include <hip/hip_runtime.h>
#include <stdint.h>
#include <stddef.h>

#define NNODES 100000
#define NEDGES 3200000
#define INFEAT 512
#define HID 256
#define SMP 32768
#define BNEPS 1e-5f
#define NCOPY 8

__device__ __forceinline__ uint32_t rotl32(uint32_t x, int d) { return (x << d) | (x >> (32 - d)); }

// Threefry-2x32, 20 rounds, JAX key-injection schedule — bit-exact, DO NOT TOUCH (verified R1)
__device__ __forceinline__ void threefry2x32(uint32_t k0, uint32_t k1, uint32_t& x0, uint32_t& x1) {
  const uint32_t ks0 = k0, ks1 = k1, ks2 = k0 ^ k1 ^ 0x1BD11BDAu;
  x0 += ks0; x1 += ks1;
#define TFR(r) { x0 += x1; x1 = rotl32(x1, r); x1 ^= x0; }
  TFR(13) TFR(15) TFR(26) TFR(6)
  x0 += ks1; x1 += ks2 + 1u;
  TFR(17) TFR(29) TFR(16) TFR(24)
  x0 += ks2; x1 += ks0 + 2u;
  TFR(13) TFR(15) TFR(26) TFR(6)
  x0 += ks0; x1 += ks1 + 3u;
  TFR(17) TFR(29) TFR(16) TFR(24)
  x0 += ks1; x1 += ks2 + 4u;
  TFR(13) TFR(15) TFR(26) TFR(6)
  x0 += ks2; x1 += ks0 + 5u;
#undef TFR
}

// Hardware XCD id (0..7 on MI355X) — wave-uniform SGPR read.
__device__ __forceinline__ int xcd_id() {
  uint32_t x;
  asm volatile("s_getreg_b32 %0, hwreg(HW_REG_XCC_ID)" : "=s"(x));
  return (int)(x & 7u);
}

// Degree histogram with XCD-private copies + L2-scope atomics.
// Copy indexed by REAL XCD id, so each copy's lines live in exactly one L2 —
// workgroup-scope atomicAdd (no sc1, executes in that L2) is atomic there and
// never produces per-op HBM write-through (the R4 failure mode: device-scope
// atomics cost ~32 B HBM write each → 99.8 MB, 127 µs).
__global__ __launch_bounds__(256) void k_deg_part(const int* __restrict__ erow, int* __restrict__ degc) {
  int* mydeg = degc + (size_t)xcd_id() * NNODES;
  const int t = blockIdx.x * 256 + threadIdx.x;       // 400128 threads, 8 edges each
  const int base = t * 8;
  if (base >= NEDGES) return;
  int4 a = *(const int4*)(erow + base);
  int4 b = *(const int4*)(erow + base + 4);
  __hip_atomic_fetch_add(&mydeg[a.x], 1, __ATOMIC_RELAXED, __HIP_MEMORY_SCOPE_WORKGROUP);
  __hip_atomic_fetch_add(&mydeg[a.y], 1, __ATOMIC_RELAXED, __HIP_MEMORY_SCOPE_WORKGROUP);
  __hip_atomic_fetch_add(&mydeg[a.z], 1, __ATOMIC_RELAXED, __HIP_MEMORY_SCOPE_WORKGROUP);
  __hip_atomic_fetch_add(&mydeg[a.w], 1, __ATOMIC_RELAXED, __HIP_MEMORY_SCOPE_WORKGROUP);
  __hip_atomic_fetch_add(&mydeg[b.x], 1, __ATOMIC_RELAXED, __HIP_MEMORY_SCOPE_WORKGROUP);
  __hip_atomic_fetch_add(&mydeg[b.y], 1, __ATOMIC_RELAXED, __HIP_MEMORY_SCOPE_WORKGROUP);
  __hip_atomic_fetch_add(&mydeg[b.z], 1, __ATOMIC_RELAXED, __HIP_MEMORY_SCOPE_WORKGROUP);
  __hip_atomic_fetch_add(&mydeg[b.w], 1, __ATOMIC_RELAXED, __HIP_MEMORY_SCOPE_WORKGROUP);
}

__global__ __launch_bounds__(256) void k_deg_reduce(const int* __restrict__ degc, int* __restrict__ deg) {
  int i = blockIdx.x * 256 + threadIdx.x;
  if (i >= NNODES) return;
  int s = 0;
#pragma unroll
  for (int c = 0; c < NCOPY; ++c) s += degc[(size_t)c * NNODES + i];
  deg[i] = s;
}

// ---- cumsum = bit-exact replica of XLA associative_scan tree, parallelized ----
__global__ __launch_bounds__(256) void k_down(const int* __restrict__ deg, float* __restrict__ E) {
  __shared__ float l0[4096];
  __shared__ float l1[2048];
  const int t = threadIdx.x;
  const int base0 = blockIdx.x * 4096;
  const int n0 = min(4096, NNODES - base0);
  for (int i = t; i < n0; i += 256) {
    float p = (float)deg[base0 + i] / 3200000.0f;  // deg.sum() exactly 3.2e6 in f32
    l0[i] = p;
    E[base0 + i] = p;
  }
  __syncthreads();
  const int b1 = base0 >> 1, n1 = min(2048, 50000 - b1);
  for (int k = t; k < n1; k += 256) { float v = l0[2*k] + l0[2*k+1]; l1[k] = v; E[100000 + b1 + k] = v; }
  __syncthreads();
  const int b2 = base0 >> 2, n2 = min(1024, 25000 - b2);
  for (int k = t; k < n2; k += 256) { float v = l1[2*k] + l1[2*k+1]; l0[k] = v; E[150000 + b2 + k] = v; }
  __syncthreads();
  const int b3 = base0 >> 3, n3 = min(512, 12500 - b3);
  for (int k = t; k < n3; k += 256) { float v = l0[2*k] + l0[2*k+1]; l1[k] = v; E[175000 + b3 + k] = v; }
  __syncthreads();
  const int b4 = base0 >> 4, n4 = min(256, 6250 - b4);
  for (int k = t; k < n4; k += 256) { float v = l1[2*k] + l1[2*k+1]; E[187500 + b4 + k] = v; }
}

__device__ __constant__ int kMidN[12] = {3125,1562,781,390,195,97,48,24,12,6,3,1};
__device__ __constant__ int kMidO[12] = {0,3125,4687,5468,5858,6053,6150,6198,6222,6234,6240,6243};
__global__ __launch_bounds__(1024) void k_mid(const float* __restrict__ E, float* __restrict__ CS) {
  __shared__ float eb[6244];
  __shared__ float sb[6244];
  const int t = threadIdx.x;
  const float* e4 = E + 187500;
  for (int k = t; k < 3125; k += 1024) eb[k] = e4[2*k] + e4[2*k+1];
  __syncthreads();
  for (int li = 1; li < 12; ++li) {
    const float* src = eb + kMidO[li-1];
    float* dst = eb + kMidO[li];
    const int n = kMidN[li];
    for (int k = t; k < n; k += 1024) dst[k] = src[2*k] + src[2*k+1];
    __syncthreads();
  }
  if (t == 0) sb[6243] = eb[6243];  // s16 = e16
  __syncthreads();
  for (int li = 10; li >= 0; --li) {
    const float* el = eb + kMidO[li];
    const float* sh = sb + kMidO[li+1];
    float* sl = sb + kMidO[li];
    const int n = kMidN[li], nh = kMidN[li+1];
    for (int k = t; k < nh; k += 1024) {
      float v = sh[k];
      sl[2*k+1] = v;
      if (2*k+2 < n) sl[2*k+2] = v + el[2*k+2];
    }
    if (t == 0) sl[0] = el[0];
    __syncthreads();
  }
  for (int k = t; k < 3125; k += 1024) CS[193750 + k] = sb[k];  // s5
}

__global__ __launch_bounds__(256) void k_up(const float* __restrict__ sh, const float* __restrict__ el,
                                            float* __restrict__ sl, int n) {
  int j = blockIdx.x * 256 + threadIdx.x;
  if (j >= n) return;
  if (j == 0) { sl[0] = el[0]; return; }
  float v = sh[(j - 1) >> 1];
  sl[j] = (j & 1) ? v : v + el[j];
}

// partitionable-threefry choice + searchsorted left — bit-exact, verified R1
__global__ __launch_bounds__(256) void k_sample(const float* __restrict__ cum, int* __restrict__ sampled,
                                                int* __restrict__ mapping, float* __restrict__ outSamp) {
  int i = blockIdx.x * 256 + threadIdx.x;
  if (i >= SMP) return;
  uint32_t x0 = 0u, x1 = (uint32_t)i;
  threefry2x32(0u, 42u, x0, x1);
  uint32_t bits = x0 ^ x1;
  float u = __uint_as_float((bits >> 9) | 0x3f800000u) - 1.0f;
  float r = cum[NNODES - 1] * (1.0f - u);
  int lo = 0, hi = NNODES;
  while (lo < hi) {
    int mid = (lo + hi) >> 1;
    if (cum[mid] < r) lo = mid + 1; else hi = mid;
  }
  if (lo > NNODES - 1) lo = NNODES - 1;
  sampled[i] = lo;
  outSamp[i] = (float)lo;
  atomicMax(&mapping[lo], i);
}

// ---- CSR build over valid edges keyed by destination position ----
__global__ __launch_bounds__(256) void k_edge_count(const int* __restrict__ erow, const int* __restrict__ ecol,
                                                    const int* __restrict__ mapping, int* __restrict__ cnt) {
  int i = blockIdx.x * 256 + threadIdx.x;
  if (i >= NEDGES) return;
  int r = mapping[erow[i]];
  int c = mapping[ecol[i]];
  if ((r | c) >= 0) atomicAdd(&cnt[c], 1);
}

__global__ __launch_bounds__(1024) void k_scan(const int* __restrict__ cnt, int* __restrict__ rowptr,
                                               int* __restrict__ cursor) {
  __shared__ int tot[1024];
  const int t = threadIdx.x;
  const int base = t * 32;
  int local[32];
  int s = 0;
#pragma unroll
  for (int i = 0; i < 32; ++i) { local[i] = s; s += cnt[base + i]; }
  tot[t] = s;
  __syncthreads();
  for (int o = 1; o < 1024; o <<= 1) {
    int v = (t >= o) ? tot[t - o] : 0;
    __syncthreads();
    tot[t] += v;
    __syncthreads();
  }
  int excl = (t == 0) ? 0 : tot[t - 1];
#pragma unroll
  for (int i = 0; i < 32; ++i) {
    int v = excl + local[i];
    rowptr[base + i] = v;
    cursor[base + i] = v;
  }
  if (t == 1023) rowptr[SMP] = tot[1023];
}

__global__ __launch_bounds__(256) void k_edge_fill(const int* __restrict__ erow, const int* __restrict__ ecol,
                                                   const int* __restrict__ mapping, int* __restrict__ cursor,
                                                   int* __restrict__ srcidx) {
  int i = blockIdx.x * 256 + threadIdx.x;
  if (i >= NEDGES) return;
  int r = mapping[erow[i]];
  int c = mapping[ecol[i]];
  if ((r | c) < 0) return;
  int pos = atomicAdd(&cursor[c], 1);
  srcidx[pos] = r;
}

// A[c,:] = sum over CSR bucket of S[r,:] — one wave per destination, no atomics
__global__ __launch_bounds__(256) void k_segsum(const float* __restrict__ S, const int* __restrict__ rowptr,
                                                const int* __restrict__ srcidx, float* __restrict__ A) {
  const int wave = threadIdx.x >> 6, lane = threadIdx.x & 63;
  const int c = blockIdx.x * 4 + wave;
  const int b = rowptr[c], e = rowptr[c + 1];
  float4 acc = make_float4(0.f, 0.f, 0.f, 0.f);
  for (int i = b; i < e; ++i) {
    int r = srcidx[i];
    float4 v = *(const float4*)(S + (size_t)r * HID + lane * 4);
    acc.x += v.x; acc.y += v.y; acc.z += v.z; acc.w += v.w;
  }
  *(float4*)(A + (size_t)c * HID + lane * 4) = acc;
}

// out[c] = sum s3[r] + b3 — one thread per destination
__global__ __launch_bounds__(256) void k_segsum_sc(const float* __restrict__ s3, const int* __restrict__ rowptr,
                                                   const int* __restrict__ srcidx, const float* __restrict__ b3,
                                                   float* __restrict__ out) {
  int c = blockIdx.x * 256 + threadIdx.x;
  if (c >= SMP) return;
  float acc = 0.f;
  const int e = rowptr[c + 1];
  for (int i = rowptr[c]; i < e; ++i) acc += s3[srcidx[i]];
  out[c] = acc + b3[0];
}

// C[M=32768, N=256] = gather(A)[.,K] @ B[K,256]; 64x64 tile, 4x4/thread, fp32
__global__ __launch_bounds__(256) void k_gemm(const float* __restrict__ Am, const float* __restrict__ Bm,
                                              float* __restrict__ Cm, const int* __restrict__ gather, int K) {
  __shared__ float As[16][68];
  __shared__ float Bs[16][64];
  const int t = threadIdx.x;
  const int tx = t & 15, ty = t >> 4;
  const int row0 = blockIdx.x * 64, col0 = blockIdx.y * 64;
  const int ar = t >> 2, ak = (t & 3) << 2;
  int arow = row0 + ar;
  if (gather) arow = gather[arow];
  const float* aptr = Am + (size_t)arow * K + ak;
  const int kb = t >> 4, cb = (t & 15) << 2;
  const float* bptr = Bm + (size_t)kb * HID + col0 + cb;
  float acc[4][4] = {};
  for (int k0 = 0; k0 < K; k0 += 16) {
    float4 av = *(const float4*)(aptr + k0);
    float4 bv = *(const float4*)(bptr + (size_t)k0 * HID);
    As[ak + 0][ar] = av.x;
    As[ak + 1][ar] = av.y;
    As[ak + 2][ar] = av.z;
    As[ak + 3][ar] = av.w;
    *(float4*)&Bs[kb][cb] = bv;
    __syncthreads();
#pragma unroll
    for (int kk = 0; kk < 16; ++kk) {
      float4 a = *(const float4*)&As[kk][ty << 2];
      float4 b = *(const float4*)&Bs[kk][tx << 2];
      acc[0][0] = fmaf(a.x, b.x, acc[0][0]); acc[0][1] = fmaf(a.x, b.y, acc[0][1]);
      acc[0][2] = fmaf(a.x, b.z, acc[0][2]); acc[0][3] = fmaf(a.x, b.w, acc[0][3]);
      acc[1][0] = fmaf(a.y, b.x, acc[1][0]); acc[1][1] = fmaf(a.y, b.y, acc[1][1]);
      acc[1][2] = fmaf(a.y, b.z, acc[1][2]); acc[1][3] = fmaf(a.y, b.w, acc[1][3]);
      acc[2][0] = fmaf(a.z, b.x, acc[2][0]); acc[2][1] = fmaf(a.z, b.y, acc[2][1]);
      acc[2][2] = fmaf(a.z, b.z, acc[2][2]); acc[2][3] = fmaf(a.z, b.w, acc[2][3]);
      acc[3][0] = fmaf(a.w, b.x, acc[3][0]); acc[3][1] = fmaf(a.w, b.y, acc[3][1]);
      acc[3][2] = fmaf(a.w, b.z, acc[3][2]); acc[3][3] = fmaf(a.w, b.w, acc[3][3]);
    }
    __syncthreads();
  }
#pragma unroll
  for (int i = 0; i < 4; ++i) {
    float4 v = make_float4(acc[i][0], acc[i][1], acc[i][2], acc[i][3]);
    *(float4*)(Cm + (size_t)(row0 + (ty << 2) + i) * HID + col0 + (tx << 2)) = v;
  }
}

__global__ __launch_bounds__(256) void k_bn_stats(const float* __restrict__ A, const float* __restrict__ bias,
                                                  float* __restrict__ sums, float* __restrict__ sumsq) {
  const int c = threadIdx.x;
  const float b = bias[c];
  float s = 0.f, q = 0.f;
  const int r0 = blockIdx.x * (SMP / 256);
  for (int r = r0; r < r0 + (SMP / 256); ++r) {
    float h = A[(size_t)r * HID + c] + b;
    s += h;
    q = fmaf(h, h, q);
  }
  unsafeAtomicAdd(&sums[c], s);
  unsafeAtomicAdd(&sumsq[c], q);
}

__global__ __launch_bounds__(256) void k_bn_final(const float* __restrict__ sums, const float* __restrict__ sumsq,
    const float* __restrict__ gamma, const float* __restrict__ beta,
    float* __restrict__ scale, float* __restrict__ shift) {
  int c = threadIdx.x;
  float mu = sums[c] * (1.0f / SMP);
  float var = fmaxf(sumsq[c] * (1.0f / SMP) - mu * mu, 0.0f);
  float sc = gamma[c] / sqrtf(var + BNEPS);
  scale[c] = sc;
  shift[c] = beta[c] - mu * sc;
}

__global__ __launch_bounds__(256) void k_bn_apply(const float* __restrict__ A, const float* __restrict__ bias,
    const float* __restrict__ scale, const float* __restrict__ shift, float* __restrict__ Hh) {
  const int total = SMP * HID / 4;
  for (int i = blockIdx.x * 256 + threadIdx.x; i < total; i += gridDim.x * 256) {
    int c = (i & (HID / 4 - 1)) * 4;
    float4 v = ((const float4*)A)[i];
    v.x = fmaxf(fmaf(v.x + bias[c + 0], scale[c + 0], shift[c + 0]), 0.f);
    v.y = fmaxf(fmaf(v.y + bias[c + 1], scale[c + 1], shift[c + 1]), 0.f);
    v.z = fmaxf(fmaf(v.z + bias[c + 2], scale[c + 2], shift[c + 2]), 0.f);
    v.w = fmaxf(fmaf(v.w + bias[c + 3], scale[c + 3], shift[c + 3]), 0.f);
    ((float4*)Hh)[i] = v;
  }
}

// s3[i] = dot(H[i,:], W3[:,0]); one wave per row
__global__ __launch_bounds__(256) void k_gemv3(const float* __restrict__ Hh, const float* __restrict__ W3,
                                               float* __restrict__ s3) {
  const int wave = threadIdx.x >> 6, lane = threadIdx.x & 63;
  const int row = blockIdx.x * 4 + wave;
  float4 h = *(const float4*)(Hh + (size_t)row * HID + lane * 4);
  float4 w = *(const float4*)(W3 + lane * 4);
  float d = h.x * w.x + h.y * w.y + h.z * w.z + h.w * w.w;
#pragma unroll
  for (int o = 32; o > 0; o >>= 1) d += __shfl_down(d, o);
  if (lane == 0) s3[row] = d;
}

extern "C" void kernel_launch(void* const* d_in, const int* in_sizes, int n_in,
                              void* d_out, int out_size, void* d_ws, size_t ws_size,
                              hipStream_t stream) {
  (void)in_sizes; (void)n_in; (void)out_size; (void)ws_size;
  const float* x   = (const float*)d_in[0];
  const int*  eidx = (const int*)d_in[1];
  const float* W1  = (const float*)d_in[2];
  const float* b1  = (const float*)d_in[3];
  const float* W2  = (const float*)d_in[4];
  const float* b2  = (const float*)d_in[5];
  const float* W3  = (const float*)d_in[6];
  const float* b3  = (const float*)d_in[7];
  const float* g1  = (const float*)d_in[8];
  const float* be1 = (const float*)d_in[9];
  const float* g2  = (const float*)d_in[10];
  const float* be2 = (const float*)d_in[11];
  const int* erow = eidx;
  const int* ecol = eidx + NEDGES;

  float* out = (float*)d_out;        // [32768] conv3 output
  float* outSamp = out + SMP;        // [32768] sampled indices as f32

  size_t off = 0;
  auto take = [&](size_t bytes) -> char* {
    char* p = (char*)d_ws + off;
    off += (bytes + 255) & ~(size_t)255;
    return p;
  };
  float* S       = (float*)take((size_t)SMP * HID * 4);  // support / s3
  float* A       = (float*)take((size_t)SMP * HID * 4);  // segsum output
  float* H       = (float*)take((size_t)SMP * HID * 4);  // post-BN activations
  float* E       = (float*)take(199994 * 4);             // down-sweep levels
  float* CS      = (float*)take(199994 * 4);             // up-sweep levels (CS[0..100000) = result)
  int*   deg     = (int*)take(NNODES * 4);
  int*   degc    = (int*)take((size_t)NCOPY * NNODES * 4);  // 3.2 MB XCD-private histograms
  int*   mapping = (int*)take(NNODES * 4);
  int*   sampled = (int*)take(SMP * 4);
  float* sums    = (float*)take(HID * 4 * 2);
  float* sumsq   = sums + HID;
  float* scale   = (float*)take(HID * 4);
  float* shift   = (float*)take(HID * 4);
  int*   cnt     = (int*)take(SMP * 4);
  int*   rowptr  = (int*)take((SMP + 1) * 4);
  int*   cursor  = (int*)take(SMP * 4);
  int*   srcidx  = (int*)take((size_t)NEDGES * 4);
  // total ws need ~= 118 MB

  hipMemsetAsync(degc, 0, (size_t)NCOPY * NNODES * 4, stream);
  hipMemsetAsync(mapping, 0xFF, NNODES * 4, stream);  // -1 everywhere
  hipMemsetAsync(cnt, 0, SMP * 4, stream);

  k_deg_part<<<(NEDGES / 8 + 255) / 256, 256, 0, stream>>>(erow, degc);
  k_deg_reduce<<<(NNODES + 255) / 256, 256, 0, stream>>>(degc, deg);

  // cumsum: parallel bit-exact tree
  k_down<<<25, 256, 0, stream>>>(deg, E);
  k_mid<<<1, 1024, 0, stream>>>(E, CS);
  k_up<<<(6250 + 255) / 256, 256, 0, stream>>>(CS + 193750, E + 187500, CS + 187500, 6250);
  k_up<<<(12500 + 255) / 256, 256, 0, stream>>>(CS + 187500, E + 175000, CS + 175000, 12500);
  k_up<<<(25000 + 255) / 256, 256, 0, stream>>>(CS + 175000, E + 150000, CS + 150000, 25000);
  k_up<<<(50000 + 255) / 256, 256, 0, stream>>>(CS + 150000, E + 100000, CS + 100000, 50000);
  k_up<<<(100000 + 255) / 256, 256, 0, stream>>>(CS + 100000, E, CS, 100000);

  k_sample<<<SMP / 256, 256, 0, stream>>>(CS, sampled, mapping, outSamp);

  // CSR over valid edges, keyed by destination position
  k_edge_count<<<(NEDGES + 255) / 256, 256, 0, stream>>>(erow, ecol, mapping, cnt);
  k_scan<<<1, 1024, 0, stream>>>(cnt, rowptr, cursor);
  k_edge_fill<<<(NEDGES + 255) / 256, 256, 0, stream>>>(erow, ecol, mapping, cursor, srcidx);

  // layer 1: conv(x@W1) -> BN -> relu
  k_gemm<<<dim3(SMP / 64, HID / 64), 256, 0, stream>>>(x, W1, S, sampled, INFEAT);
  k_segsum<<<SMP / 4, 256, 0, stream>>>(S, rowptr, srcidx, A);
  hipMemsetAsync(sums, 0, HID * 4 * 2, stream);
  k_bn_stats<<<256, 256, 0, stream>>>(A, b1, sums, sumsq);
  k_bn_final<<<1, HID, 0, stream>>>(sums, sumsq, g1, be1, scale, shift);
  k_bn_apply<<<2048, 256, 0, stream>>>(A, b1, scale, shift, H);

  // layer 2
  k_gemm<<<dim3(SMP / 64, HID / 64), 256, 0, stream>>>(H, W2, S, nullptr, HID);
  k_segsum<<<SMP / 4, 256, 0, stream>>>(S, rowptr, srcidx, A);
  hipMemsetAsync(sums, 0, HID * 4 * 2, stream);
  k_bn_stats<<<256, 256, 0, stream>>>(A, b2, sums, sumsq);
  k_bn_final<<<1, HID, 0, stream>>>(sums, sumsq, g2, be2, scale, shift);
  k_bn_apply<<<2048, 256, 0, stream>>>(A, b2, scale, shift, H);

  // layer 3: gemv + CSR segsum + bias
  k_gemv3<<<SMP / 4, 256, 0, stream>>>(H, W3, S);  // S reused as s3
  k_segsum_sc<<<SMP / 256, 256, 0, stream>>>(S, rowptr, srcidx, b3, out);
}

// Round 6
// 726.968 us; speedup vs baseline: 1.1244x; 1.1158x over previous
//
#include <hip/hip_runtime.h>
#include <stdint.h>
#include <stddef.h>

#define NNODES 100000
#define NEDGES 3200000
#define INFEAT 512
#define HID 256
#define SMP 32768
#define BNEPS 1e-5f

// ---- degree histogram partition params ----
#define PA_EPB 4096                                   // edges per phase-A block
#define PA_BLOCKS ((NEDGES + PA_EPB - 1) / PA_EPB)    // 782
#define NBUCK 196                                     // bucket = node >> 9 (512 nodes/bucket)
#define BBITS 9

__device__ __forceinline__ uint32_t rotl32(uint32_t x, int d) { return (x << d) | (x >> (32 - d)); }

// Threefry-2x32, 20 rounds, JAX key-injection schedule — bit-exact, DO NOT TOUCH (verified R1)
__device__ __forceinline__ void threefry2x32(uint32_t k0, uint32_t k1, uint32_t& x0, uint32_t& x1) {
  const uint32_t ks0 = k0, ks1 = k1, ks2 = k0 ^ k1 ^ 0x1BD11BDAu;
  x0 += ks0; x1 += ks1;
#define TFR(r) { x0 += x1; x1 = rotl32(x1, r); x1 ^= x0; }
  TFR(13) TFR(15) TFR(26) TFR(6)
  x0 += ks1; x1 += ks2 + 1u;
  TFR(17) TFR(29) TFR(16) TFR(24)
  x0 += ks2; x1 += ks0 + 2u;
  TFR(13) TFR(15) TFR(26) TFR(6)
  x0 += ks0; x1 += ks1 + 3u;
  TFR(17) TFR(29) TFR(16) TFR(24)
  x0 += ks1; x1 += ks2 + 4u;
  TFR(13) TFR(15) TFR(26) TFR(6)
  x0 += ks2; x1 += ks0 + 5u;
#undef TFR
}

// Phase A: block-local bucket sort of 4096 edges via LDS; zero global atomics.
// (R4/R5 post-mortem: every global atomic RMW costs ~32B TCC write-through
// regardless of scope/privatization — 3.2M atomics = 99.8MB = 127µs. So: none.)
__global__ __launch_bounds__(256) void k_part(const int* __restrict__ erow,
                                              int* __restrict__ part, int* __restrict__ lbaseg) {
  __shared__ int hist[NBUCK];
  __shared__ int cnt2[NBUCK];
  __shared__ int base[NBUCK];
  __shared__ int sc[256];
  __shared__ int staged[PA_EPB];
  const int t = threadIdx.x;
  const int s = blockIdx.x;
  const int e0 = s * PA_EPB;
  const int n = min(PA_EPB, NEDGES - e0);
  for (int i = t; i < NBUCK; i += 256) { hist[i] = 0; cnt2[i] = 0; }
  __syncthreads();
  int nodes[16];
  int cnt = 0;
  for (int i = t; i < n; i += 256) nodes[cnt++] = erow[e0 + i];   // coalesced
  for (int j = 0; j < cnt; ++j) atomicAdd(&hist[nodes[j] >> BBITS], 1);  // LDS atomic
  __syncthreads();
  sc[t] = (t < NBUCK) ? hist[t] : 0;
  __syncthreads();
  for (int o = 1; o < 256; o <<= 1) {
    int v = (t >= o) ? sc[t - o] : 0;
    __syncthreads();
    sc[t] += v;
    __syncthreads();
  }
  if (t < NBUCK) {
    base[t] = sc[t] - hist[t];                 // exclusive prefix
    lbaseg[s * NBUCK + t] = base[t];
  }
  __syncthreads();
  for (int j = 0; j < cnt; ++j) {
    int b = nodes[j] >> BBITS;
    int r = atomicAdd(&cnt2[b], 1);            // LDS atomic
    staged[base[b] + r] = nodes[j];
  }
  __syncthreads();
  for (int i = t; i < n; i += 256) part[e0 + i] = staged[i];      // coalesced
}

// Phase B: one block per bucket (512 nodes); gather chunks from all 782 segments,
// LDS histogram, non-atomic deg write.
__global__ __launch_bounds__(256) void k_count(const int* __restrict__ part,
                                               const int* __restrict__ lbaseg, int* __restrict__ deg) {
  __shared__ int hist[512];
  const int t = threadIdx.x;
  const int b = blockIdx.x;
  for (int i = t; i < 512; i += 256) hist[i] = 0;
  __syncthreads();
  for (int s = t; s < PA_BLOCKS; s += 256) {
    const int e0 = s * PA_EPB;
    const int n = min(PA_EPB, NEDGES - e0);
    const int st = lbaseg[s * NBUCK + b];
    const int en = (b < NBUCK - 1) ? lbaseg[s * NBUCK + b + 1] : n;
    for (int i = st; i < en; ++i) {
      int node = part[e0 + i];
      atomicAdd(&hist[node & 511], 1);         // LDS atomic
    }
  }
  __syncthreads();
  const int n0 = b << BBITS;
  for (int i = t; i < 512; i += 256) {
    int idx = n0 + i;
    if (idx < NNODES) deg[idx] = hist[i];
  }
}

// ---- cumsum = bit-exact replica of XLA associative_scan tree, parallelized ----
__global__ __launch_bounds__(256) void k_down(const int* __restrict__ deg, float* __restrict__ E) {
  __shared__ float l0[4096];
  __shared__ float l1[2048];
  const int t = threadIdx.x;
  const int base0 = blockIdx.x * 4096;
  const int n0 = min(4096, NNODES - base0);
  for (int i = t; i < n0; i += 256) {
    float p = (float)deg[base0 + i] / 3200000.0f;  // deg.sum() exactly 3.2e6 in f32
    l0[i] = p;
    E[base0 + i] = p;
  }
  __syncthreads();
  const int b1 = base0 >> 1, n1 = min(2048, 50000 - b1);
  for (int k = t; k < n1; k += 256) { float v = l0[2*k] + l0[2*k+1]; l1[k] = v; E[100000 + b1 + k] = v; }
  __syncthreads();
  const int b2 = base0 >> 2, n2 = min(1024, 25000 - b2);
  for (int k = t; k < n2; k += 256) { float v = l1[2*k] + l1[2*k+1]; l0[k] = v; E[150000 + b2 + k] = v; }
  __syncthreads();
  const int b3 = base0 >> 3, n3 = min(512, 12500 - b3);
  for (int k = t; k < n3; k += 256) { float v = l0[2*k] + l0[2*k+1]; l1[k] = v; E[175000 + b3 + k] = v; }
  __syncthreads();
  const int b4 = base0 >> 4, n4 = min(256, 6250 - b4);
  for (int k = t; k < n4; k += 256) { float v = l1[2*k] + l1[2*k+1]; E[187500 + b4 + k] = v; }
}

__device__ __constant__ int kMidN[12] = {3125,1562,781,390,195,97,48,24,12,6,3,1};
__device__ __constant__ int kMidO[12] = {0,3125,4687,5468,5858,6053,6150,6198,6222,6234,6240,6243};
__global__ __launch_bounds__(1024) void k_mid(const float* __restrict__ E, float* __restrict__ CS) {
  __shared__ float eb[6244];
  __shared__ float sb[6244];
  const int t = threadIdx.x;
  const float* e4 = E + 187500;
  for (int k = t; k < 3125; k += 1024) eb[k] = e4[2*k] + e4[2*k+1];
  __syncthreads();
  for (int li = 1; li < 12; ++li) {
    const float* src = eb + kMidO[li-1];
    float* dst = eb + kMidO[li];
    const int n = kMidN[li];
    for (int k = t; k < n; k += 1024) dst[k] = src[2*k] + src[2*k+1];
    __syncthreads();
  }
  if (t == 0) sb[6243] = eb[6243];  // s16 = e16
  __syncthreads();
  for (int li = 10; li >= 0; --li) {
    const float* el = eb + kMidO[li];
    const float* sh = sb + kMidO[li+1];
    float* sl = sb + kMidO[li];
    const int n = kMidN[li], nh = kMidN[li+1];
    for (int k = t; k < nh; k += 1024) {
      float v = sh[k];
      sl[2*k+1] = v;
      if (2*k+2 < n) sl[2*k+2] = v + el[2*k+2];
    }
    if (t == 0) sl[0] = el[0];
    __syncthreads();
  }
  for (int k = t; k < 3125; k += 1024) CS[193750 + k] = sb[k];  // s5
}

__global__ __launch_bounds__(256) void k_up(const float* __restrict__ sh, const float* __restrict__ el,
                                            float* __restrict__ sl, int n) {
  int j = blockIdx.x * 256 + threadIdx.x;
  if (j >= n) return;
  if (j == 0) { sl[0] = el[0]; return; }
  float v = sh[(j - 1) >> 1];
  sl[j] = (j & 1) ? v : v + el[j];
}

// partitionable-threefry choice + searchsorted left — bit-exact, verified R1
__global__ __launch_bounds__(256) void k_sample(const float* __restrict__ cum, int* __restrict__ sampled,
                                                int* __restrict__ mapping, float* __restrict__ outSamp) {
  int i = blockIdx.x * 256 + threadIdx.x;
  if (i >= SMP) return;
  uint32_t x0 = 0u, x1 = (uint32_t)i;
  threefry2x32(0u, 42u, x0, x1);
  uint32_t bits = x0 ^ x1;
  float u = __uint_as_float((bits >> 9) | 0x3f800000u) - 1.0f;
  float r = cum[NNODES - 1] * (1.0f - u);
  int lo = 0, hi = NNODES;
  while (lo < hi) {
    int mid = (lo + hi) >> 1;
    if (cum[mid] < r) lo = mid + 1; else hi = mid;
  }
  if (lo > NNODES - 1) lo = NNODES - 1;
  sampled[i] = lo;
  outSamp[i] = (float)lo;
  atomicMax(&mapping[lo], i);
}

// ---- CSR build over valid edges keyed by destination position ----
__global__ __launch_bounds__(256) void k_edge_count(const int* __restrict__ erow, const int* __restrict__ ecol,
                                                    const int* __restrict__ mapping, int* __restrict__ cnt) {
  int i = blockIdx.x * 256 + threadIdx.x;
  if (i >= NEDGES) return;
  int r = mapping[erow[i]];
  int c = mapping[ecol[i]];
  if ((r | c) >= 0) atomicAdd(&cnt[c], 1);
}

__global__ __launch_bounds__(1024) void k_scan(const int* __restrict__ cnt, int* __restrict__ rowptr,
                                               int* __restrict__ cursor) {
  __shared__ int tot[1024];
  const int t = threadIdx.x;
  const int base = t * 32;
  int local[32];
  int s = 0;
#pragma unroll
  for (int i = 0; i < 32; ++i) { local[i] = s; s += cnt[base + i]; }
  tot[t] = s;
  __syncthreads();
  for (int o = 1; o < 1024; o <<= 1) {
    int v = (t >= o) ? tot[t - o] : 0;
    __syncthreads();
    tot[t] += v;
    __syncthreads();
  }
  int excl = (t == 0) ? 0 : tot[t - 1];
#pragma unroll
  for (int i = 0; i < 32; ++i) {
    int v = excl + local[i];
    rowptr[base + i] = v;
    cursor[base + i] = v;
  }
  if (t == 1023) rowptr[SMP] = tot[1023];
}

__global__ __launch_bounds__(256) void k_edge_fill(const int* __restrict__ erow, const int* __restrict__ ecol,
                                                   const int* __restrict__ mapping, int* __restrict__ cursor,
                                                   int* __restrict__ srcidx) {
  int i = blockIdx.x * 256 + threadIdx.x;
  if (i >= NEDGES) return;
  int r = mapping[erow[i]];
  int c = mapping[ecol[i]];
  if ((r | c) < 0) return;
  int pos = atomicAdd(&cursor[c], 1);
  srcidx[pos] = r;
}

// A[c,:] = sum over CSR bucket of S[r,:] — one wave per destination, no atomics
__global__ __launch_bounds__(256) void k_segsum(const float* __restrict__ S, const int* __restrict__ rowptr,
                                                const int* __restrict__ srcidx, float* __restrict__ A) {
  const int wave = threadIdx.x >> 6, lane = threadIdx.x & 63;
  const int c = blockIdx.x * 4 + wave;
  const int b = rowptr[c], e = rowptr[c + 1];
  float4 acc = make_float4(0.f, 0.f, 0.f, 0.f);
  for (int i = b; i < e; ++i) {
    int r = srcidx[i];
    float4 v = *(const float4*)(S + (size_t)r * HID + lane * 4);
    acc.x += v.x; acc.y += v.y; acc.z += v.z; acc.w += v.w;
  }
  *(float4*)(A + (size_t)c * HID + lane * 4) = acc;
}

// out[c] = sum s3[r] + b3 — one thread per destination
__global__ __launch_bounds__(256) void k_segsum_sc(const float* __restrict__ s3, const int* __restrict__ rowptr,
                                                   const int* __restrict__ srcidx, const float* __restrict__ b3,
                                                   float* __restrict__ out) {
  int c = blockIdx.x * 256 + threadIdx.x;
  if (c >= SMP) return;
  float acc = 0.f;
  const int e = rowptr[c + 1];
  for (int i = rowptr[c]; i < e; ++i) acc += s3[srcidx[i]];
  out[c] = acc + b3[0];
}

// C[M=32768, N=256] = gather(A)[.,K] @ B[K,256]; 64x64 tile, 4x4/thread, fp32
__global__ __launch_bounds__(256) void k_gemm(const float* __restrict__ Am, const float* __restrict__ Bm,
                                              float* __restrict__ Cm, const int* __restrict__ gather, int K) {
  __shared__ float As[16][68];
  __shared__ float Bs[16][64];
  const int t = threadIdx.x;
  const int tx = t & 15, ty = t >> 4;
  const int row0 = blockIdx.x * 64, col0 = blockIdx.y * 64;
  const int ar = t >> 2, ak = (t & 3) << 2;
  int arow = row0 + ar;
  if (gather) arow = gather[arow];
  const float* aptr = Am + (size_t)arow * K + ak;
  const int kb = t >> 4, cb = (t & 15) << 2;
  const float* bptr = Bm + (size_t)kb * HID + col0 + cb;
  float acc[4][4] = {};
  for (int k0 = 0; k0 < K; k0 += 16) {
    float4 av = *(const float4*)(aptr + k0);
    float4 bv = *(const float4*)(bptr + (size_t)k0 * HID);
    As[ak + 0][ar] = av.x;
    As[ak + 1][ar] = av.y;
    As[ak + 2][ar] = av.z;
    As[ak + 3][ar] = av.w;
    *(float4*)&Bs[kb][cb] = bv;
    __syncthreads();
#pragma unroll
    for (int kk = 0; kk < 16; ++kk) {
      float4 a = *(const float4*)&As[kk][ty << 2];
      float4 b = *(const float4*)&Bs[kk][tx << 2];
      acc[0][0] = fmaf(a.x, b.x, acc[0][0]); acc[0][1] = fmaf(a.x, b.y, acc[0][1]);
      acc[0][2] = fmaf(a.x, b.z, acc[0][2]); acc[0][3] = fmaf(a.x, b.w, acc[0][3]);
      acc[1][0] = fmaf(a.y, b.x, acc[1][0]); acc[1][1] = fmaf(a.y, b.y, acc[1][1]);
      acc[1][2] = fmaf(a.y, b.z, acc[1][2]); acc[1][3] = fmaf(a.y, b.w, acc[1][3]);
      acc[2][0] = fmaf(a.z, b.x, acc[2][0]); acc[2][1] = fmaf(a.z, b.y, acc[2][1]);
      acc[2][2] = fmaf(a.z, b.z, acc[2][2]); acc[2][3] = fmaf(a.z, b.w, acc[2][3]);
      acc[3][0] = fmaf(a.w, b.x, acc[3][0]); acc[3][1] = fmaf(a.w, b.y, acc[3][1]);
      acc[3][2] = fmaf(a.w, b.z, acc[3][2]); acc[3][3] = fmaf(a.w, b.w, acc[3][3]);
    }
    __syncthreads();
  }
#pragma unroll
  for (int i = 0; i < 4; ++i) {
    float4 v = make_float4(acc[i][0], acc[i][1], acc[i][2], acc[i][3]);
    *(float4*)(Cm + (size_t)(row0 + (ty << 2) + i) * HID + col0 + (tx << 2)) = v;
  }
}

__global__ __launch_bounds__(256) void k_bn_stats(const float* __restrict__ A, const float* __restrict__ bias,
                                                  float* __restrict__ sums, float* __restrict__ sumsq) {
  const int c = threadIdx.x;
  const float b = bias[c];
  float s = 0.f, q = 0.f;
  const int r0 = blockIdx.x * (SMP / 256);
  for (int r = r0; r < r0 + (SMP / 256); ++r) {
    float h = A[(size_t)r * HID + c] + b;
    s += h;
    q = fmaf(h, h, q);
  }
  unsafeAtomicAdd(&sums[c], s);
  unsafeAtomicAdd(&sumsq[c], q);
}

__global__ __launch_bounds__(256) void k_bn_final(const float* __restrict__ sums, const float* __restrict__ sumsq,
    const float* __restrict__ gamma, const float* __restrict__ beta,
    float* __restrict__ scale, float* __restrict__ shift) {
  int c = threadIdx.x;
  float mu = sums[c] * (1.0f / SMP);
  float var = fmaxf(sumsq[c] * (1.0f / SMP) - mu * mu, 0.0f);
  float sc = gamma[c] / sqrtf(var + BNEPS);
  scale[c] = sc;
  shift[c] = beta[c] - mu * sc;
}

__global__ __launch_bounds__(256) void k_bn_apply(const float* __restrict__ A, const float* __restrict__ bias,
    const float* __restrict__ scale, const float* __restrict__ shift, float* __restrict__ Hh) {
  const int total = SMP * HID / 4;
  for (int i = blockIdx.x * 256 + threadIdx.x; i < total; i += gridDim.x * 256) {
    int c = (i & (HID / 4 - 1)) * 4;
    float4 v = ((const float4*)A)[i];
    v.x = fmaxf(fmaf(v.x + bias[c + 0], scale[c + 0], shift[c + 0]), 0.f);
    v.y = fmaxf(fmaf(v.y + bias[c + 1], scale[c + 1], shift[c + 1]), 0.f);
    v.z = fmaxf(fmaf(v.z + bias[c + 2], scale[c + 2], shift[c + 2]), 0.f);
    v.w = fmaxf(fmaf(v.w + bias[c + 3], scale[c + 3], shift[c + 3]), 0.f);
    ((float4*)Hh)[i] = v;
  }
}

// s3[i] = dot(H[i,:], W3[:,0]); one wave per row
__global__ __launch_bounds__(256) void k_gemv3(const float* __restrict__ Hh, const float* __restrict__ W3,
                                               float* __restrict__ s3) {
  const int wave = threadIdx.x >> 6, lane = threadIdx.x & 63;
  const int row = blockIdx.x * 4 + wave;
  float4 h = *(const float4*)(Hh + (size_t)row * HID + lane * 4);
  float4 w = *(const float4*)(W3 + lane * 4);
  float d = h.x * w.x + h.y * w.y + h.z * w.z + h.w * w.w;
#pragma unroll
  for (int o = 32; o > 0; o >>= 1) d += __shfl_down(d, o);
  if (lane == 0) s3[row] = d;
}

extern "C" void kernel_launch(void* const* d_in, const int* in_sizes, int n_in,
                              void* d_out, int out_size, void* d_ws, size_t ws_size,
                              hipStream_t stream) {
  (void)in_sizes; (void)n_in; (void)out_size; (void)ws_size;
  const float* x   = (const float*)d_in[0];
  const int*  eidx = (const int*)d_in[1];
  const float* W1  = (const float*)d_in[2];
  const float* b1  = (const float*)d_in[3];
  const float* W2  = (const float*)d_in[4];
  const float* b2  = (const float*)d_in[5];
  const float* W3  = (const float*)d_in[6];
  const float* b3  = (const float*)d_in[7];
  const float* g1  = (const float*)d_in[8];
  const float* be1 = (const float*)d_in[9];
  const float* g2  = (const float*)d_in[10];
  const float* be2 = (const float*)d_in[11];
  const int* erow = eidx;
  const int* ecol = eidx + NEDGES;

  float* out = (float*)d_out;        // [32768] conv3 output
  float* outSamp = out + SMP;        // [32768] sampled indices as f32

  size_t off = 0;
  auto take = [&](size_t bytes) -> char* {
    char* p = (char*)d_ws + off;
    off += (bytes + 255) & ~(size_t)255;
    return p;
  };
  float* S       = (float*)take((size_t)SMP * HID * 4);  // support / s3
  float* A       = (float*)take((size_t)SMP * HID * 4);  // segsum output
  float* H       = (float*)take((size_t)SMP * HID * 4);  // post-BN activations
  float* E       = (float*)take(199994 * 4);             // down-sweep levels
  float* CS      = (float*)take(199994 * 4);             // up-sweep levels (CS[0..100000) = result)
  int*   deg     = (int*)take(NNODES * 4);
  int*   part    = (int*)take((size_t)NEDGES * 4);       // bucket-partitioned edge rows
  int*   lbaseg  = (int*)take((size_t)PA_BLOCKS * NBUCK * 4);  // per-block bucket bases
  int*   mapping = (int*)take(NNODES * 4);
  int*   sampled = (int*)take(SMP * 4);
  float* sums    = (float*)take(HID * 4 * 2);
  float* sumsq   = sums + HID;
  float* scale   = (float*)take(HID * 4);
  float* shift   = (float*)take(HID * 4);
  int*   cnt     = (int*)take(SMP * 4);
  int*   rowptr  = (int*)take((SMP + 1) * 4);
  int*   cursor  = (int*)take(SMP * 4);
  int*   srcidx  = (int*)take((size_t)NEDGES * 4);
  // total ws need ~= 130 MB

  hipMemsetAsync(mapping, 0xFF, NNODES * 4, stream);  // -1 everywhere
  hipMemsetAsync(cnt, 0, SMP * 4, stream);

  // degree histogram, atomic-free (two-phase partition)
  k_part<<<PA_BLOCKS, 256, 0, stream>>>(erow, part, lbaseg);
  k_count<<<NBUCK, 256, 0, stream>>>(part, lbaseg, deg);

  // cumsum: parallel bit-exact tree
  k_down<<<25, 256, 0, stream>>>(deg, E);
  k_mid<<<1, 1024, 0, stream>>>(E, CS);
  k_up<<<(6250 + 255) / 256, 256, 0, stream>>>(CS + 193750, E + 187500, CS + 187500, 6250);
  k_up<<<(12500 + 255) / 256, 256, 0, stream>>>(CS + 187500, E + 175000, CS + 175000, 12500);
  k_up<<<(25000 + 255) / 256, 256, 0, stream>>>(CS + 175000, E + 150000, CS + 150000, 25000);
  k_up<<<(50000 + 255) / 256, 256, 0, stream>>>(CS + 150000, E + 100000, CS + 100000, 50000);
  k_up<<<(100000 + 255) / 256, 256, 0, stream>>>(CS + 100000, E, CS, 100000);

  k_sample<<<SMP / 256, 256, 0, stream>>>(CS, sampled, mapping, outSamp);

  // CSR over valid edges, keyed by destination position
  k_edge_count<<<(NEDGES + 255) / 256, 256, 0, stream>>>(erow, ecol, mapping, cnt);
  k_scan<<<1, 1024, 0, stream>>>(cnt, rowptr, cursor);
  k_edge_fill<<<(NEDGES + 255) / 256, 256, 0, stream>>>(erow, ecol, mapping, cursor, srcidx);

  // layer 1: conv(x@W1) -> BN -> relu
  k_gemm<<<dim3(SMP / 64, HID / 64), 256, 0, stream>>>(x, W1, S, sampled, INFEAT);
  k_segsum<<<SMP / 4, 256, 0, stream>>>(S, rowptr, srcidx, A);
  hipMemsetAsync(sums, 0, HID * 4 * 2, stream);
  k_bn_stats<<<256, 256, 0, stream>>>(A, b1, sums, sumsq);
  k_bn_final<<<1, HID, 0, stream>>>(sums, sumsq, g1, be1, scale, shift);
  k_bn_apply<<<2048, 256, 0, stream>>>(A, b1, scale, shift, H);

  // layer 2
  k_gemm<<<dim3(SMP / 64, HID / 64), 256, 0, stream>>>(H, W2, S, nullptr, HID);
  k_segsum<<<SMP / 4, 256, 0, stream>>>(S, rowptr, srcidx, A);
  hipMemsetAsync(sums, 0, HID * 4 * 2, stream);
  k_bn_stats<<<256, 256, 0, stream>>>(A, b2, sums, sumsq);
  k_bn_final<<<1, HID, 0, stream>>>(sums, sumsq, g2, be2, scale, shift);
  k_bn_apply<<<2048, 256, 0, stream>>>(A, b2, scale, shift, H);

  // layer 3: gemv + CSR segsum + bias
  k_gemv3<<<SMP / 4, 256, 0, stream>>>(H, W3, S);  // S reused as s3
  k_segsum_sc<<<SMP / 256, 256, 0, stream>>>(S, rowptr, srcidx, b3, out);
}